// Round 15
// baseline (888.055 us; speedup 1.0000x reference)
//
#include <hip/hip_runtime.h>
#include <hip/hip_bf16.h>

typedef unsigned short ushort_t;
typedef unsigned int uint_t;
typedef __attribute__((ext_vector_type(8))) short short8;
typedef __attribute__((ext_vector_type(4))) float float4v;

static constexpr int NN  = 100000;   // nodes
static constexpr int NE  = 400000;   // edges
static constexpr int NB  = 500;      // graphs
static constexpr int NS  = 75;       // seeds
static constexpr int H   = 128;
static constexpr int NBK = 16;       // src buckets per node (NN/NBK = 6250)
static constexpr int BKW = NN/NBK;   // 6250
static constexpr float SCALE = 0.08838834764831845f; // 1/sqrt(128)

union U32 { uint_t u; float f; };
__device__ __forceinline__ float bf2f(ushort_t b){ U32 t; t.u = ((uint_t)b) << 16; return t.f; }
__device__ __forceinline__ ushort_t f2bf(float f){
    U32 t; t.f = f;
    uint_t r = t.u + 0x7fffu + ((t.u >> 16) & 1u);   // RNE
    return (ushort_t)(r >> 16);
}
__device__ __forceinline__ void fma8(float* a, uint4 u, float c){
    a[0] += c * bf2f((ushort_t)(u.x & 0xffff)); a[1] += c * bf2f((ushort_t)(u.x >> 16));
    a[2] += c * bf2f((ushort_t)(u.y & 0xffff)); a[3] += c * bf2f((ushort_t)(u.y >> 16));
    a[4] += c * bf2f((ushort_t)(u.z & 0xffff)); a[5] += c * bf2f((ushort_t)(u.z >> 16));
    a[6] += c * bf2f((ushort_t)(u.w & 0xffff)); a[7] += c * bf2f((ushort_t)(u.w >> 16));
}

// ================= bucketed CSR build (key = dst*16 + src/6250) =================
__global__ void k_zero_i(int* __restrict__ p, int n){
    int i = blockIdx.x*256 + threadIdx.x;
    if (i < n) p[i] = 0;
}
__global__ void k_hist2(int* counts2, const int* __restrict__ src,
                        const int* __restrict__ dst, int e){
    int i = blockIdx.x*256 + threadIdx.x;
    if (i < e){
        int s = src[i], d = dst[i];
        atomicAdd(&counts2[d*NBK + s/BKW], 1);
    }
}
__global__ __launch_bounds__(256) void k_scan1b(const int* __restrict__ counts,
    int* __restrict__ row_start, int* __restrict__ blockSums, int n){
    __shared__ int s[256];
    int t = threadIdx.x, i = blockIdx.x*256 + t;
    int v = (i < n) ? counts[i] : 0;
    s[t] = v; __syncthreads();
    #pragma unroll
    for (int off = 1; off < 256; off <<= 1){
        int add = (t >= off) ? s[t-off] : 0;
        __syncthreads();
        s[t] += add;
        __syncthreads();
    }
    if (i < n) row_start[i] = s[t] - v;
    if (t == 255) blockSums[blockIdx.x] = s[255];
}
// single-block exclusive running scan, in place
__global__ __launch_bounds__(256) void k_scan_lin(int* __restrict__ a, int n){
    __shared__ int s[256];
    __shared__ int carry;
    int t = threadIdx.x;
    if (t == 0) carry = 0;
    __syncthreads();
    for (int base = 0; base < n; base += 256){
        int i = base + t;
        int v = (i < n) ? a[i] : 0;
        s[t] = v; __syncthreads();
        #pragma unroll
        for (int off = 1; off < 256; off <<= 1){
            int add = (t >= off) ? s[t-off] : 0;
            __syncthreads();
            s[t] += add;
            __syncthreads();
        }
        if (i < n) a[i] = s[t] - v + carry;
        __syncthreads();
        if (t == 0) carry += s[255];
        __syncthreads();
    }
}
__global__ void k_scan3b(int* __restrict__ row2, int* __restrict__ cursor,
                         const int* __restrict__ blockOff, int n, int total){
    int i = blockIdx.x*256 + threadIdx.x;
    if (i < n){
        int v = row2[i] + blockOff[i >> 8];
        row2[i] = v; cursor[i] = v;
    }
    if (i == 0) row2[n] = total;
}
__global__ void k_norms2(const int* __restrict__ row2, float* __restrict__ dinv,
                         float* __restrict__ selfc, int n){
    int i = blockIdx.x*256 + threadIdx.x;
    if (i < n){
        int deg = row2[(i+1)*NBK] - row2[i*NBK];
        float r = rsqrtf(1.f + (float)deg);
        dinv[i] = r; selfc[i] = r*r;
    }
}
__global__ void k_fillcsr2(const int* __restrict__ src, const int* __restrict__ dst,
    const float* __restrict__ dinv, int* cursor,
    int* __restrict__ srcs_s, float* __restrict__ ce_s, int e){
    int i = blockIdx.x*256 + threadIdx.x;
    if (i < e){
        int d = dst[i], s = src[i];
        int p = atomicAdd(&cursor[d*NBK + s/BKW], 1);
        srcs_s[p] = s;
        ce_s[p] = dinv[s] * dinv[d];
    }
}

// ================= merged conversions =================
struct CvtArgs { const float* w[17]; const float* w0; const float* s1; const float* s2; const float* x37; };
static constexpr int CVT_W   = 17*16384;
static constexpr int CVT_W0  = 8192;
static constexpr int CVT_S1  = 9600;
static constexpr int CVT_S2  = 128;
static constexpr int CVT_X   = NN*64;
__global__ void k_cvt_all(CvtArgs a, ushort_t* __restrict__ wbf, ushort_t* __restrict__ w0bf,
                          ushort_t* __restrict__ s1bf, ushort_t* __restrict__ s2bf,
                          ushort_t* __restrict__ xb64){
    int i = blockIdx.x*256 + threadIdx.x;
    if (i < CVT_W){ int idx = i >> 14, off = i & 16383; wbf[i] = f2bf(a.w[idx][off]); return; }
    i -= CVT_W;
    if (i < CVT_W0){ int r = i >> 6, c = i & 63; w0bf[i] = (c < 37) ? f2bf(a.w0[r*37 + c]) : (ushort_t)0; return; }
    i -= CVT_W0;
    if (i < CVT_S1){ s1bf[i] = f2bf(a.s1[i]); return; }
    i -= CVT_S1;
    if (i < CVT_S2){ s2bf[i] = f2bf(a.s2[i]); return; }
    i -= CVT_S2;
    if (i < CVT_X){ int r = i >> 6, c = i & 63; xb64[i] = (c < 37) ? f2bf(a.x37[(size_t)r*37 + c]) : (ushort_t)0; return; }
}

// ========== seed-Q projections ==========
__global__ __launch_bounds__(256) void k_seedq(
    const ushort_t* __restrict__ s1bf, const ushort_t* __restrict__ s2bf,
    const ushort_t* __restrict__ W1, const float* __restrict__ bias1,
    const ushort_t* __restrict__ W2q, const float* __restrict__ bias2,
    ushort_t* __restrict__ q0, ushort_t* __restrict__ q2)
{
    int blk = blockIdx.x;
    const ushort_t* x = (blk < 2) ? s1bf : s2bf;
    const ushort_t* W = (blk < 2) ? W1 : W2q;
    const float* bias = (blk < 2) ? bias1 : bias2;
    ushort_t* out = (blk < 2) ? q0 : q2;
    int M = (blk < 2) ? NS : 1;
    int base = (blk < 2) ? blk*64 : 0;
    int tid  = threadIdx.x;
    int wid  = tid >> 6;
    int lane = tid & 63;
    int l15  = lane & 15, quad = lane >> 4;
    int row0 = base + wid*16;
    int ar   = row0 + l15; if (ar > M-1) ar = M-1;
    const short* xr = (const short*)(x + (size_t)ar*H) + quad*8;
    float4v acc[8];
    #pragma unroll
    for (int i = 0; i < 8; ++i) acc[i] = (float4v)0.f;
    #pragma unroll
    for (int kc = 0; kc < 4; ++kc){
        short8 a = *(const short8*)(xr + kc*32);
        #pragma unroll
        for (int nt = 0; nt < 8; ++nt){
            short8 b = *(const short8*)((const short*)(W + (size_t)(nt*16 + l15)*H) + kc*32 + quad*8);
            acc[nt] = __builtin_amdgcn_mfma_f32_16x16x32_bf16(a, b, acc[nt], 0, 0, 0);
        }
    }
    #pragma unroll
    for (int nt = 0; nt < 8; ++nt){
        int c = nt*16 + l15;
        float bv = bias[c];
        #pragma unroll
        for (int reg = 0; reg < 4; ++reg){
            int r = row0 + quad*4 + reg;
            if (r >= M) continue;
            out[(size_t)r*H + c] = f2bf(acc[nt][reg] + bv);
        }
    }
}

// ========== two-stage GEMM: y = x + relu(x@Wfo+bfo); then N outputs SEQUENTIALLY ==========
template<int NOUT2>
__global__ __launch_bounds__(256, 4) void gemm_fo_then(
    const ushort_t* __restrict__ x, int M,
    const ushort_t* __restrict__ Wfo, const float* __restrict__ bfo,
    const ushort_t* __restrict__ W2,
    const float* __restrict__ b20, const float* __restrict__ b21, const float* __restrict__ b22,
    ushort_t* __restrict__ o0, ushort_t* __restrict__ o1, ushort_t* __restrict__ o2,
    float* __restrict__ o32)
{
    __shared__ ushort_t As[64][136];
    const int tid = threadIdx.x, w = tid >> 6, lane = tid & 63;
    const int l15 = lane & 15, quad = lane >> 4;
    const int row0 = blockIdx.x*64 + w*16;
    int ar = row0 + l15; if (ar > M-1) ar = M-1;
    const short* xr = (const short*)(x + (size_t)ar*H) + quad*8;
    {
        float4v acc[8];
        #pragma unroll
        for (int i = 0; i < 8; ++i) acc[i] = (float4v)0.f;
        #pragma unroll
        for (int kc = 0; kc < 4; ++kc){
            short8 a = *(const short8*)(xr + kc*32);
            #pragma unroll
            for (int nt = 0; nt < 8; ++nt){
                short8 b = *(const short8*)((const short*)(Wfo + (size_t)(nt*16 + l15)*H) + kc*32 + quad*8);
                acc[nt] = __builtin_amdgcn_mfma_f32_16x16x32_bf16(a, b, acc[nt], 0, 0, 0);
            }
        }
        #pragma unroll
        for (int nt = 0; nt < 8; ++nt){
            int c = nt*16 + l15;
            float bv = bfo[c];
            #pragma unroll
            for (int reg = 0; reg < 4; ++reg){
                int r = row0 + quad*4 + reg;
                float v = 0.f;
                if (r < M) v = fmaxf(acc[nt][reg] + bv, 0.f) + bf2f(x[(size_t)r*H + c]);
                As[w*16 + quad*4 + reg][c] = f2bf(v);
            }
        }
    }
    __syncthreads();
    #pragma unroll 1
    for (int n = 0; n < NOUT2; ++n){
        float4v o[8];
        #pragma unroll
        for (int i = 0; i < 8; ++i) o[i] = (float4v)0.f;
        #pragma unroll
        for (int kc = 0; kc < 4; ++kc){
            short8 a = *(const short8*)(&As[w*16 + l15][kc*32 + quad*8]);
            #pragma unroll
            for (int nt = 0; nt < 8; ++nt){
                short8 b = *(const short8*)((const short*)(W2 + (size_t)((n*8 + nt)*16 + l15)*H) + kc*32 + quad*8);
                o[nt] = __builtin_amdgcn_mfma_f32_16x16x32_bf16(a, b, o[nt], 0, 0, 0);
            }
        }
        ushort_t* out = (n == 0) ? o0 : ((n == 1) ? o1 : o2);
        const float* bb = (n == 0) ? b20 : ((n == 1) ? b21 : b22);
        #pragma unroll
        for (int nt = 0; nt < 8; ++nt){
            int c = nt*16 + l15;
            float bv = bb[c];
            #pragma unroll
            for (int reg = 0; reg < 4; ++reg){
                int r = row0 + quad*4 + reg;
                if (r >= M) continue;
                float v = o[nt][reg] + bv;
                if (o32 && n == 0) o32[(size_t)r*H + c] = v;
                else               out[(size_t)r*H + c] = f2bf(v);
            }
        }
    }
}

// ========== fused gather + MFMA GEMM (bucketed CSR: row_st stride NBK) ==========
template<int NOUT, int RELU, int STAGE2, int MINW>
__global__ __launch_bounds__(256, MINW) void k_conv_fused3(
    const ushort_t* __restrict__ x,
    const int* __restrict__ row_st, const int* __restrict__ srcs,
    const float* __restrict__ ces, const float* __restrict__ selfc,
    const ushort_t* __restrict__ W, const float* __restrict__ bias0,
    const float* __restrict__ bias1,
    const ushort_t* __restrict__ W2, const float* __restrict__ bias2,
    ushort_t* __restrict__ out0, ushort_t* __restrict__ out1)
{
    __shared__ ushort_t As[32][136];
    __shared__ ushort_t Bs[(NOUT==16)?32:1][(NOUT==16)?136:1];
    const int tid = threadIdx.x;
    const int node = tid >> 3, qq = tid & 7;
    const int g = blockIdx.x*32 + node;
    float acc[16];
    #pragma unroll
    for (int i = 0; i < 16; ++i) acc[i] = 0.f;
    if (g < NN){
        const uint4* xr = (const uint4*)(x + (size_t)g*H + qq*16);
        float sc = selfc[g];
        uint4 u0 = xr[0], u1 = xr[1];
        fma8(acc+0, u0, sc); fma8(acc+8, u1, sc);
        int e = row_st[g*NBK], e1 = row_st[g*NBK + NBK];
        int sA = 0, sB = 0; float cA = 0.f, cB = 0.f;
        if (e < e1){ sA = srcs[e]; cA = ces[e]; }
        if (e + 1 < e1){ sB = srcs[e+1]; cB = ces[e+1]; }
        while (e + 2 <= e1){
            int sA2 = 0, sB2 = 0; float cA2 = 0.f, cB2 = 0.f;
            if (e + 2 < e1){ sA2 = srcs[e+2]; cA2 = ces[e+2]; }
            if (e + 3 < e1){ sB2 = srcs[e+3]; cB2 = ces[e+3]; }
            const uint4* pa = (const uint4*)(x + (size_t)sA*H + qq*16);
            const uint4* pb = (const uint4*)(x + (size_t)sB*H + qq*16);
            uint4 a0 = pa[0], a1 = pa[1];
            uint4 c0 = pb[0], c1 = pb[1];
            fma8(acc+0, a0, cA); fma8(acc+8, a1, cA);
            fma8(acc+0, c0, cB); fma8(acc+8, c1, cB);
            sA = sA2; sB = sB2; cA = cA2; cB = cB2;
            e += 2;
        }
        if (e < e1){
            const uint4* pa = (const uint4*)(x + (size_t)sA*H + qq*16);
            uint4 a0 = pa[0], a1 = pa[1];
            fma8(acc+0, a0, cA); fma8(acc+8, a1, cA);
        }
    }
    {
        uint_t* dst = (uint_t*)&As[node][qq*16];
        #pragma unroll
        for (int i = 0; i < 8; ++i)
            dst[i] = (uint_t)f2bf(acc[2*i]) | ((uint_t)f2bf(acc[2*i+1]) << 16);
    }
    __syncthreads();
    const int w = tid >> 6, lane = tid & 63, l15 = lane & 15, quad = lane >> 4;
    const int rt = w & 1;
    constexpr int NT = NOUT/2;
    const int ct0 = (w >> 1) * NT;
    float4v o[NT];
    #pragma unroll
    for (int t = 0; t < NT; ++t) o[t] = (float4v)0.f;
    #pragma unroll
    for (int kc = 0; kc < 4; ++kc){
        short8 a = *(const short8*)(&As[rt*16 + l15][kc*32 + quad*8]);
        #pragma unroll
        for (int t = 0; t < NT; ++t){
            short8 bfr = *(const short8*)(W + (size_t)((ct0 + t)*16 + l15)*H + kc*32 + quad*8);
            o[t] = __builtin_amdgcn_mfma_f32_16x16x32_bf16(a, bfr, o[t], 0, 0, 0);
        }
    }
    __syncthreads();
    #pragma unroll
    for (int t = 0; t < NT; ++t){
        int cg = (ct0 + t)*16 + l15;
        #pragma unroll
        for (int r = 0; r < 4; ++r){
            float v;
            if (NOUT == 8 || cg < 128){
                v = o[t][r] + bias0[cg];
                if (RELU) v = fmaxf(v, 0.f);
                As[rt*16 + quad*4 + r][cg] = f2bf(v);
            } else {
                v = o[t][r] + bias1[cg - 128];
                if (RELU) v = fmaxf(v, 0.f);
                Bs[rt*16 + quad*4 + r][cg - 128] = f2bf(v);
            }
        }
    }
    __syncthreads();
    if (STAGE2){
        float4v o2[4];
        #pragma unroll
        for (int t = 0; t < 4; ++t) o2[t] = (float4v)0.f;
        const int ct2 = (w >> 1) * 4;
        #pragma unroll
        for (int kc = 0; kc < 4; ++kc){
            short8 a = *(const short8*)(&As[rt*16 + l15][kc*32 + quad*8]);
            #pragma unroll
            for (int t = 0; t < 4; ++t){
                short8 bfr = *(const short8*)(W2 + (size_t)((ct2 + t)*16 + l15)*H + kc*32 + quad*8);
                o2[t] = __builtin_amdgcn_mfma_f32_16x16x32_bf16(a, bfr, o2[t], 0, 0, 0);
            }
        }
        __syncthreads();
        #pragma unroll
        for (int t = 0; t < 4; ++t){
            int cg = (ct2 + t)*16 + l15;
            #pragma unroll
            for (int r = 0; r < 4; ++r)
                As[rt*16 + quad*4 + r][cg] = f2bf(o2[t][r] + bias2[cg]);
        }
        __syncthreads();
    }
    if (g < NN){
        uint4* op = (uint4*)(out0 + (size_t)g*H + qq*16);
        const uint4* sp = (const uint4*)&As[node][qq*16];
        op[0] = sp[0]; op[1] = sp[1];
        if (NOUT == 16){
            uint4* oq = (uint4*)(out1 + (size_t)g*H + qq*16);
            const uint4* sq = (const uint4*)&Bs[node][qq*16];
            oq[0] = sq[0]; oq[1] = sq[1];
        }
    }
}

// ========== conv0: gather padded-64 bf16 rows + MFMA GEMM (K=64), bucketed CSR ==========
__global__ __launch_bounds__(256, 8) void k_conv0b(
    const ushort_t* __restrict__ x,
    const int* __restrict__ row_st, const int* __restrict__ srcs,
    const float* __restrict__ ces, const float* __restrict__ selfc,
    const ushort_t* __restrict__ W,
    const float* __restrict__ bias,
    ushort_t* __restrict__ out)
{
    __shared__ ushort_t As[32][136];
    const int tid = threadIdx.x;
    const int node = tid >> 3, qq = tid & 7;
    const int g = blockIdx.x*32 + node;
    float acc[8];
    #pragma unroll
    for (int i = 0; i < 8; ++i) acc[i] = 0.f;
    if (g < NN){
        const uint4* xr = (const uint4*)(x + (size_t)g*64 + qq*8);
        float sc = selfc[g];
        fma8(acc, xr[0], sc);
        int e = row_st[g*NBK], e1 = row_st[g*NBK + NBK];
        int sA = 0, sB = 0; float cA = 0.f, cB = 0.f;
        if (e < e1){ sA = srcs[e]; cA = ces[e]; }
        if (e + 1 < e1){ sB = srcs[e+1]; cB = ces[e+1]; }
        while (e + 2 <= e1){
            int sA2 = 0, sB2 = 0; float cA2 = 0.f, cB2 = 0.f;
            if (e + 2 < e1){ sA2 = srcs[e+2]; cA2 = ces[e+2]; }
            if (e + 3 < e1){ sB2 = srcs[e+3]; cB2 = ces[e+3]; }
            uint4 a0 = *(const uint4*)(x + (size_t)sA*64 + qq*8);
            uint4 c0 = *(const uint4*)(x + (size_t)sB*64 + qq*8);
            fma8(acc, a0, cA);
            fma8(acc, c0, cB);
            sA = sA2; sB = sB2; cA = cA2; cB = cB2;
            e += 2;
        }
        if (e < e1){
            uint4 a0 = *(const uint4*)(x + (size_t)sA*64 + qq*8);
            fma8(acc, a0, cA);
        }
    }
    {
        uint_t* dst = (uint_t*)&As[node][qq*8];
        #pragma unroll
        for (int i = 0; i < 4; ++i)
            dst[i] = (uint_t)f2bf(acc[2*i]) | ((uint_t)f2bf(acc[2*i+1]) << 16);
    }
    __syncthreads();
    const int w = tid >> 6, lane = tid & 63, l15 = lane & 15, quad = lane >> 4;
    const int rt = w & 1;
    const int ct0 = (w >> 1) * 4;
    float4v o[4];
    #pragma unroll
    for (int t = 0; t < 4; ++t) o[t] = (float4v)0.f;
    #pragma unroll
    for (int kc = 0; kc < 2; ++kc){
        short8 a = *(const short8*)(&As[rt*16 + l15][kc*32 + quad*8]);
        #pragma unroll
        for (int t = 0; t < 4; ++t){
            short8 bfr = *(const short8*)(W + (size_t)((ct0 + t)*16 + l15)*64 + kc*32 + quad*8);
            o[t] = __builtin_amdgcn_mfma_f32_16x16x32_bf16(a, bfr, o[t], 0, 0, 0);
        }
    }
    __syncthreads();
    #pragma unroll
    for (int t = 0; t < 4; ++t){
        int cg = (ct0 + t)*16 + l15;
        #pragma unroll
        for (int r = 0; r < 4; ++r)
            As[rt*16 + quad*4 + r][cg] = f2bf(fmaxf(o[t][r] + bias[cg], 0.f));
    }
    __syncthreads();
    if (g < NN){
        uint4* op = (uint4*)(out + (size_t)g*H + qq*16);
        const uint4* sp = (const uint4*)&As[node][qq*16];
        op[0] = sp[0]; op[1] = sp[1];
    }
}

// ========== MFMA flash attention ==========
template<int NK>
__global__ __launch_bounds__(256) void k_attn_mfma(
    const ushort_t* __restrict__ Q, int qbs,
    const ushort_t* __restrict__ K, const ushort_t* __restrict__ V,
    ushort_t* __restrict__ out, int nq)
{
    constexpr int NKT = (NK + 15) / 16;
    constexpr int NKC = (NK + 31) / 32;
    __shared__ ushort_t Ks[2][208][24];
    __shared__ ushort_t Vs[2][16][232];
    __shared__ ushort_t Ps[4][16][232];
    int b = blockIdx.x >> 2, hp = blockIdx.x & 3;
    int h0 = hp*2;
    int tid = threadIdx.x;
    {
        uint_t* p = (uint_t*)&Ps[0][0][0];
        for (int i = tid; i < 4*16*232/2; i += 256) p[i] = 0;
    }
    const ushort_t* Kb = K + (size_t)b*NK*H + h0*16;
    for (int idx = tid; idx < NK*8; idx += 256){
        int key = idx >> 3, p = idx & 7;
        int hh = p >> 2, dl = (p & 3)*4;
        const uint_t* src = (const uint_t*)(Kb + (size_t)key*H + hh*16 + dl);
        uint_t* d = (uint_t*)&Ks[hh][key][dl];
        d[0] = src[0]; d[1] = src[1];
    }
    const ushort_t* Vb = V + (size_t)b*NK*H + h0*16;
    for (int idx = tid; idx < NK*8; idx += 256){
        int key = idx >> 3, p = idx & 7;
        int hh = p >> 2, dl = (p & 3)*4;
        const ushort_t* src = Vb + (size_t)key*H + hh*16 + dl;
        Vs[hh][dl+0][key] = src[0];
        Vs[hh][dl+1][key] = src[1];
        Vs[hh][dl+2][key] = src[2];
        Vs[hh][dl+3][key] = src[3];
    }
    for (int idx = tid; idx < 2*16*(232-NK); idx += 256){
        int key = NK + idx % (232-NK), r = idx / (232-NK);
        Vs[r>>4][r&15][key] = 0;
    }
    __syncthreads();

    int w = tid >> 6, lane = tid & 63;
    int hh = w >> 1, half = w & 1;
    int h = h0 + hh;
    int l15 = lane & 15, quad = lane >> 4;
    bool klow = (quad < 2);
    int nqt = (nq + 15) >> 4;
    int split = (nqt + 1) >> 1;
    int qt0 = half ? split : 0;
    int qt1 = half ? nqt : split;
    for (int qt = qt0; qt < qt1; ++qt){
        int qr = qt*16 + l15; if (qr > nq-1) qr = nq-1;
        short8 av = *(const short8*)(Q + (size_t)b*qbs + (size_t)qr*H + h*16 + (quad & 1)*8);
        short8 zero8 = (short8)0;
        short8 afrag = klow ? av : zero8;
        float4v s[NKT];
        #pragma unroll
        for (int kt = 0; kt < NKT; ++kt){
            short8 bv = *(const short8*)(&Ks[hh][kt*16 + l15][(quad & 1)*8]);
            short8 bfrag = klow ? bv : zero8;
            s[kt] = __builtin_amdgcn_mfma_f32_16x16x32_bf16(afrag, bfrag, (float4v)0.f, 0, 0, 0);
        }
        float mx[4] = {-1e30f, -1e30f, -1e30f, -1e30f};
        #pragma unroll
        for (int kt = 0; kt < NKT; ++kt){
            if (kt*16 + l15 >= NK){ s[kt][0]=-1e30f; s[kt][1]=-1e30f; s[kt][2]=-1e30f; s[kt][3]=-1e30f; }
            #pragma unroll
            for (int r = 0; r < 4; ++r) mx[r] = fmaxf(mx[r], s[kt][r]);
        }
        #pragma unroll
        for (int off = 1; off < 16; off <<= 1){
            #pragma unroll
            for (int r = 0; r < 4; ++r) mx[r] = fmaxf(mx[r], __shfl_xor(mx[r], off));
        }
        float sum[4] = {0.f, 0.f, 0.f, 0.f};
        #pragma unroll
        for (int kt = 0; kt < NKT; ++kt){
            #pragma unroll
            for (int r = 0; r < 4; ++r){
                float e = __expf((s[kt][r] - mx[r]) * SCALE);
                sum[r] += e;
                Ps[w][quad*4 + r][kt*16 + l15] = f2bf(e);
            }
        }
        #pragma unroll
        for (int off = 1; off < 16; off <<= 1){
            #pragma unroll
            for (int r = 0; r < 4; ++r) sum[r] += __shfl_xor(sum[r], off);
        }
        float4v o = (float4v)0.f;
        #pragma unroll
        for (int kc = 0; kc < NKC; ++kc){
            short8 pa = *(const short8*)(&Ps[w][l15][kc*32 + quad*8]);
            short8 vb = *(const short8*)(&Vs[hh][l15][kc*32 + quad*8]);
            o = __builtin_amdgcn_mfma_f32_16x16x32_bf16(pa, vb, o, 0, 0, 0);
        }
        #pragma unroll
        for (int r = 0; r < 4; ++r){
            int row = qt*16 + quad*4 + r;
            if (row < nq){
                float qv = bf2f(Q[(size_t)b*qbs + (size_t)row*H + h*16 + l15]);
                out[((size_t)b*nq + row)*H + h*16 + l15] = f2bf(qv + o[r] / sum[r]);
            }
        }
    }
}

// ---------------- hERG (fp32) ----------------
__global__ void k_herg(const float* __restrict__ em, const float* __restrict__ W,
                       const float* __restrict__ b, float* __restrict__ outv)
{
    __shared__ float e[1280];
    int t = threadIdx.x;
    for (int i = t; i < 1280; i += 128) e[i] = em[i];
    __syncthreads();
    float acc = 0.f;
    for (int k = 0; k < 1280; ++k) acc += e[k] * W[(size_t)t*1280 + k];
    outv[t] = fmaxf(acc + b[t], 0.f);
}

// ---------------- head MLP (fp32) ----------------
__global__ __launch_bounds__(128) void k_final(const float* __restrict__ lin2out,
    const float* __restrict__ hergv,
    const float* __restrict__ hoW, const float* __restrict__ hob,
    const float* __restrict__ fcW, const float* __restrict__ fcb,
    const float* __restrict__ sW,  const float* __restrict__ sb,
    float* __restrict__ outp)
{
    int b = blockIdx.x, t = threadIdx.x;
    __shared__ float v256[256];
    __shared__ float tt[128];
    __shared__ float red[128];
    v256[t]       = lin2out[(size_t)b*H + t];
    v256[128 + t] = hergv[t];
    __syncthreads();
    float acc = 0.f;
    for (int k = 0; k < 256; ++k) acc += v256[k] * hoW[(size_t)t*256 + k];
    tt[t] = fmaxf(acc + hob[t], 0.f);
    __syncthreads();
    acc = 0.f;
    for (int k = 0; k < 128; ++k) acc += tt[k] * fcW[(size_t)t*128 + k];
    float uv = fmaxf(acc + fcb[t], 0.f);
    red[t] = uv * sW[t];
    __syncthreads();
    for (int s = 64; s > 0; s >>= 1){
        if (t < s) red[t] += red[t + s];
        __syncthreads();
    }
    if (t == 0){
        float logit = red[0] + sb[0];
        outp[b] = 1.f / (1.f + expf(-logit));
    }
}

extern "C" void kernel_launch(void* const* d_in, const int* in_sizes, int n_in,
                              void* d_out, int out_size, void* d_ws, size_t ws_size,
                              hipStream_t stream)
{
    (void)in_sizes; (void)n_in; (void)out_size; (void)ws_size;
    const float* herg_em = (const float*)d_in[0];
    const float* x_in    = (const float*)d_in[1];
    const float* convW[4] = {(const float*)d_in[4], (const float*)d_in[6], (const float*)d_in[8], (const float*)d_in[10]};
    const float* convB[4] = {(const float*)d_in[5], (const float*)d_in[7], (const float*)d_in[9], (const float*)d_in[11]};
    const float* lin1W = (const float*)d_in[12]; const float* lin1b = (const float*)d_in[13];
    const float* lin2W = (const float*)d_in[14]; const float* lin2b = (const float*)d_in[15];
    const float* S1    = (const float*)d_in[16];
    const float* p1fqW = (const float*)d_in[17]; const float* p1fqb = (const float*)d_in[18];
    const float* p1kW  = (const float*)d_in[19]; const float* p1kb  = (const float*)d_in[20];
    const float* p1vW  = (const float*)d_in[21]; const float* p1vb  = (const float*)d_in[22];
    const float* p1foW = (const float*)d_in[23]; const float* p1fob = (const float*)d_in[24];
    const float* sfqW  = (const float*)d_in[25]; const float* sfqb  = (const float*)d_in[26];
    const float* skW   = (const float*)d_in[27]; const float* skb   = (const float*)d_in[28];
    const float* svW   = (const float*)d_in[29]; const float* svb   = (const float*)d_in[30];
    const float* sfoW  = (const float*)d_in[31]; const float* sfob  = (const float*)d_in[32];
    const float* p2fqW = (const float*)d_in[33]; const float* p2fqb = (const float*)d_in[34];
    const float* p2kW  = (const float*)d_in[35]; const float* p2kb  = (const float*)d_in[36];
    const float* p2vW  = (const float*)d_in[37]; const float* p2vb  = (const float*)d_in[38];
    const float* p2foW = (const float*)d_in[39]; const float* p2fob = (const float*)d_in[40];
    const float* S2    = (const float*)d_in[41];
    const float* hlW   = (const float*)d_in[42]; const float* hlb   = (const float*)d_in[43];
    const float* hoW   = (const float*)d_in[44]; const float* hob   = (const float*)d_in[45];
    const float* fcW   = (const float*)d_in[46]; const float* fcb   = (const float*)d_in[47];
    const float* sW    = (const float*)d_in[48]; const float* sb    = (const float*)d_in[49];
    const int*  ei    = (const int*)d_in[50];
    const int*  esrc  = ei;
    const int*  edst  = ei + NE;
    float* outp = (float*)d_out;

    // -------- workspace layout (byte offsets, 16B-aligned) --------
    char* WS = (char*)d_ws;
    int*   row2   = (int*)(WS + 0);            // NN*16+1 ints = 6,400,004 B
    float* dinv   = (float*)(WS + 6400016);    // 400,000
    float* selfc  = (float*)(WS + 6800016);    // 400,000
    int*   srcs_s = (int*)(WS + 7200016);      // 1,600,000
    float* ce_s   = (float*)(WS + 8800016);    // 1,600,000
    ushort_t* wbf = (ushort_t*)(WS + 10400016);// 557,056
    ushort_t* w0bf= (ushort_t*)(WS + 10957072);// 16,384
    ushort_t* s1bf= (ushort_t*)(WS + 10973456);// 19,200
    ushort_t* s2bf= (ushort_t*)(WS + 10992656);// 256
    ushort_t* q0  = (ushort_t*)(WS + 10992912);// 19,200
    ushort_t* q2  = (ushort_t*)(WS + 11012112);// 256
    float* hergv  = (float*)(WS + 11012368);   // 512
    float* l2out  = (float*)(WS + 11012880);   // 256,000
    ushort_t* xb64= (ushort_t*)(WS + 11268880);// 12,800,000
    ushort_t* b0  = (ushort_t*)(WS + 24068880);// 25,600,000
    ushort_t* b1  = (ushort_t*)(WS + 49668880);
    ushort_t* b2  = (ushort_t*)(WS + 75268880);
    ushort_t* xA  = (ushort_t*)(WS + 100868880); // 9,601,024
    ushort_t* xB  = (ushort_t*)(WS + 110469904); // 9,601,024
    int*   bSums  = (int*)(WS + 120070928);      // 6250 ints
    // build-time aliases (dead before xA/xB are first written):
    int*   counts2 = (int*)xA;                 // NN*16 ints = 6.4 MB
    int*   cursor2 = (int*)xB;                 // NN*16 ints

    const int n2   = NN*NBK;               // 1,600,000
    const int gN   = (NN + 255)/256;       // 391
    const int gN2  = n2/256;               // 6250 exact
    const int gE   = (NE + 255)/256;       // 1563
    const int gC   = (NN + 31)/32;         // 3125
    const int gXb  = (NB*NS + 63)/64;      // 586

    // ---- bucketed CSR build ----
    k_zero_i <<<gN2, 256, 0, stream>>>(counts2, n2);
    k_hist2  <<<gE, 256, 0, stream>>>(counts2, esrc, edst, NE);
    k_scan1b <<<gN2, 256, 0, stream>>>(counts2, row2, bSums, n2);
    k_scan_lin<<<1, 256, 0, stream>>>(bSums, gN2);
    k_scan3b <<<gN2, 256, 0, stream>>>(row2, cursor2, bSums, n2, NE);
    k_norms2 <<<gN, 256, 0, stream>>>(row2, dinv, selfc, NN);
    k_fillcsr2<<<gE, 256, 0, stream>>>(esrc, edst, dinv, cursor2, srcs_s, ce_s, NE);

    // ---- merged weight/input conversions (1 launch) ----
    CvtArgs ca;
    ca.w[0]=convW[1]; ca.w[1]=convW[2]; ca.w[2]=convW[3]; ca.w[3]=lin1W; ca.w[4]=lin2W;
    ca.w[5]=p1kW; ca.w[6]=p1vW; ca.w[7]=p1foW;
    ca.w[8]=sfqW; ca.w[9]=skW; ca.w[10]=svW; ca.w[11]=sfoW;
    ca.w[12]=p2kW; ca.w[13]=p2vW; ca.w[14]=p2foW; ca.w[15]=p1fqW; ca.w[16]=p2fqW;
    ca.w0 = convW[0]; ca.s1 = S1; ca.s2 = S2; ca.x37 = x_in;
    const int cvtTotal = CVT_W + CVT_W0 + CVT_S1 + CVT_S2 + CVT_X;
    k_cvt_all<<<(cvtTotal + 255)/256, 256, 0, stream>>>(ca, wbf, w0bf, s1bf, s2bf, xb64);

    // ---- seed-Q projections (1 launch) + hERG ----
    k_seedq<<<3, 256, 0, stream>>>(s1bf, s2bf, wbf + (size_t)15*16384, p1fqb,
                                   wbf + (size_t)16*16384, p2fqb, q0, q2);
    k_herg<<<1, 128, 0, stream>>>(herg_em, hlW, hlb, hergv);

    // ---- conv0 (fused gather64 + GEMM) -> b0 ----
    k_conv0b<<<gC, 256, 0, stream>>>(xb64, row2, srcs_s, ce_s, selfc, w0bf, convB[0], b0);
    // ---- conv1, conv2 ----
    k_conv_fused3<8,1,0,8><<<gC, 256, 0, stream>>>(b0, row2, srcs_s, ce_s, selfc,
        wbf + (size_t)0*16384, convB[1], nullptr, nullptr, nullptr, b1, nullptr);
    k_conv_fused3<8,1,0,8><<<gC, 256, 0, stream>>>(b1, row2, srcs_s, ce_s, selfc,
        wbf + (size_t)1*16384, convB[2], nullptr, nullptr, nullptr, b0, nullptr);
    // ---- conv3 + lin1 fused -> hx in b1 ----
    k_conv_fused3<8,1,1,8><<<gC, 256, 0, stream>>>(b0, row2, srcs_s, ce_s, selfc,
        wbf + (size_t)2*16384, convB[3], nullptr, wbf + (size_t)3*16384, lin1b, b1, nullptr);
    // ---- pma1 K,V: fused shared-gather + dual GEMM (K->b2, V->b0) ----
    k_conv_fused3<16,0,0,4><<<gC, 256, 0, stream>>>(b1, row2, srcs_s, ce_s, selfc,
        wbf + (size_t)5*16384, p1kb, p1vb, nullptr, nullptr, b2, b0);
    // ---- GMPool_G attention -> xA ----
    k_attn_mfma<200><<<NB*4, 256, 0, stream>>>(q0, 0, b2, b0, xA, NS);
    // ---- fused: xb1 = xA + relu(xA@p1fo+b); then SAB Q,K,V (into b0,b1,b2) ----
    gemm_fo_then<3><<<gXb, 256, 0, stream>>>(xA, NB*NS, wbf + (size_t)7*16384, p1fob,
        wbf + (size_t)8*16384, sfqb, skb, svb, b0, b1, b2, nullptr);
    // ---- SAB attention -> xB ----
    k_attn_mfma<75><<<NB*4, 256, 0, stream>>>(b0, NS*H, b1, b2, xB, NS);
    // ---- fused: xb2 = xB + relu(xB@sfo+b); then PMA2 K,V (into b1,b2) ----
    gemm_fo_then<2><<<gXb, 256, 0, stream>>>(xB, NB*NS, wbf + (size_t)11*16384, sfob,
        wbf + (size_t)12*16384, p2kb, p2vb, nullptr, b1, b2, nullptr, nullptr);
    // ---- GMPool_I attention -> xA [500,128] ----
    k_attn_mfma<75><<<NB*4, 256, 0, stream>>>(q2, 0, b1, b2, xA, 1);
    // ---- fused: xb3 = xA + relu(xA@p2fo+b); then lin2 (fp32 out) ----
    gemm_fo_then<1><<<(NB+63)/64, 256, 0, stream>>>(xA, NB, wbf + (size_t)14*16384, p2fob,
        wbf + (size_t)4*16384, lin2b, nullptr, nullptr, nullptr, nullptr, nullptr, l2out);
    // ---- head ----
    k_final<<<NB, 128, 0, stream>>>(l2out, hergv, hoW, hob, fcW, fcb, sW, sb, outp);
}

// Round 16
// 819.110 us; speedup vs baseline: 1.0842x; 1.0842x over previous
//
#include <hip/hip_runtime.h>
#include <hip/hip_bf16.h>

typedef unsigned short ushort_t;
typedef unsigned int uint_t;
typedef __attribute__((ext_vector_type(8))) short short8;
typedef __attribute__((ext_vector_type(4))) float float4v;

static constexpr int NN  = 100000;   // nodes
static constexpr int NE  = 400000;   // edges
static constexpr int NB  = 500;      // graphs
static constexpr int NS  = 75;       // seeds
static constexpr int H   = 128;
static constexpr float SCALE = 0.08838834764831845f; // 1/sqrt(128)

union U32 { uint_t u; float f; };
__device__ __forceinline__ float bf2f(ushort_t b){ U32 t; t.u = ((uint_t)b) << 16; return t.f; }
__device__ __forceinline__ ushort_t f2bf(float f){
    U32 t; t.f = f;
    uint_t r = t.u + 0x7fffu + ((t.u >> 16) & 1u);   // RNE
    return (ushort_t)(r >> 16);
}
__device__ __forceinline__ void fma8(float* a, uint4 u, float c){
    a[0] += c * bf2f((ushort_t)(u.x & 0xffff)); a[1] += c * bf2f((ushort_t)(u.x >> 16));
    a[2] += c * bf2f((ushort_t)(u.y & 0xffff)); a[3] += c * bf2f((ushort_t)(u.y >> 16));
    a[4] += c * bf2f((ushort_t)(u.z & 0xffff)); a[5] += c * bf2f((ushort_t)(u.z >> 16));
    a[6] += c * bf2f((ushort_t)(u.w & 0xffff)); a[7] += c * bf2f((ushort_t)(u.w >> 16));
}

// ================= CSR build =================
__global__ void k_zero_i(int* __restrict__ p, int n){
    int i = blockIdx.x*256 + threadIdx.x;
    if (i < n) p[i] = 0;
}
__global__ void k_hist(int* counts, const int* __restrict__ dst, int e){
    int i = blockIdx.x*256 + threadIdx.x;
    if (i < e) atomicAdd(&counts[dst[i]], 1);
}
// scan + degree norms fused
__global__ __launch_bounds__(256) void k_scan1(const int* __restrict__ counts,
    int* __restrict__ row_start, int* __restrict__ blockSums,
    float* __restrict__ dinv, float* __restrict__ selfc, int n){
    __shared__ int s[256];
    int t = threadIdx.x, i = blockIdx.x*256 + t;
    int v = (i < n) ? counts[i] : 0;
    s[t] = v; __syncthreads();
    #pragma unroll
    for (int off = 1; off < 256; off <<= 1){
        int add = (t >= off) ? s[t-off] : 0;
        __syncthreads();
        s[t] += add;
        __syncthreads();
    }
    if (i < n){
        row_start[i] = s[t] - v;
        float r = rsqrtf(1.f + (float)v);
        dinv[i] = r; selfc[i] = r*r;
    }
    if (t == 255) blockSums[blockIdx.x] = s[255];
}
__global__ __launch_bounds__(512) void k_scan2(const int* __restrict__ blockSums,
    int* __restrict__ blockOff, int nb){
    __shared__ int s[512];
    int t = threadIdx.x;
    int v = (t < nb) ? blockSums[t] : 0;
    s[t] = v; __syncthreads();
    #pragma unroll
    for (int off = 1; off < 512; off <<= 1){
        int add = (t >= off) ? s[t-off] : 0;
        __syncthreads();
        s[t] += add;
        __syncthreads();
    }
    blockOff[t] = s[t] - v;
}
__global__ void k_scan3(int* __restrict__ row_start, int* __restrict__ cursor,
                        const int* __restrict__ blockOff, int n, int total){
    int i = blockIdx.x*256 + threadIdx.x;
    if (i < n){
        int v = row_start[i] + blockOff[i >> 8];
        row_start[i] = v; cursor[i] = v;
    }
    if (i == 0) row_start[n] = total;
}
__global__ void k_fillcsr(const int* __restrict__ src, const int* __restrict__ dst,
    const float* __restrict__ dinv, int* cursor,
    int* __restrict__ srcs_s, float* __restrict__ ce_s, int e){
    int i = blockIdx.x*256 + threadIdx.x;
    if (i < e){
        int d = dst[i], s = src[i];
        int p = atomicAdd(&cursor[d], 1);
        srcs_s[p] = s;
        ce_s[p] = dinv[s] * dinv[d];
    }
}

// ================= merged conversions =================
struct CvtArgs { const float* w[17]; const float* w0; const float* s1; const float* s2; const float* x37; };
static constexpr int CVT_W   = 17*16384;
static constexpr int CVT_W0  = 8192;
static constexpr int CVT_S1  = 9600;
static constexpr int CVT_S2  = 128;
static constexpr int CVT_X   = NN*64;
__global__ void k_cvt_all(CvtArgs a, ushort_t* __restrict__ wbf, ushort_t* __restrict__ w0bf,
                          ushort_t* __restrict__ s1bf, ushort_t* __restrict__ s2bf,
                          ushort_t* __restrict__ xb64){
    int i = blockIdx.x*256 + threadIdx.x;
    if (i < CVT_W){ int idx = i >> 14, off = i & 16383; wbf[i] = f2bf(a.w[idx][off]); return; }
    i -= CVT_W;
    if (i < CVT_W0){ int r = i >> 6, c = i & 63; w0bf[i] = (c < 37) ? f2bf(a.w0[r*37 + c]) : (ushort_t)0; return; }
    i -= CVT_W0;
    if (i < CVT_S1){ s1bf[i] = f2bf(a.s1[i]); return; }
    i -= CVT_S1;
    if (i < CVT_S2){ s2bf[i] = f2bf(a.s2[i]); return; }
    i -= CVT_S2;
    if (i < CVT_X){ int r = i >> 6, c = i & 63; xb64[i] = (c < 37) ? f2bf(a.x37[(size_t)r*37 + c]) : (ushort_t)0; return; }
}

// ========== seed-Q projections: blocks 0-1 -> S1@p1fq (75 rows), block 2 -> S2@p2fq (1 row) ==========
__global__ __launch_bounds__(256) void k_seedq(
    const ushort_t* __restrict__ s1bf, const ushort_t* __restrict__ s2bf,
    const ushort_t* __restrict__ W1, const float* __restrict__ bias1,
    const ushort_t* __restrict__ W2q, const float* __restrict__ bias2,
    ushort_t* __restrict__ q0, ushort_t* __restrict__ q2)
{
    int blk = blockIdx.x;
    const ushort_t* x = (blk < 2) ? s1bf : s2bf;
    const ushort_t* W = (blk < 2) ? W1 : W2q;
    const float* bias = (blk < 2) ? bias1 : bias2;
    ushort_t* out = (blk < 2) ? q0 : q2;
    int M = (blk < 2) ? NS : 1;
    int base = (blk < 2) ? blk*64 : 0;
    int tid  = threadIdx.x;
    int wid  = tid >> 6;
    int lane = tid & 63;
    int l15  = lane & 15, quad = lane >> 4;
    int row0 = base + wid*16;
    int ar   = row0 + l15; if (ar > M-1) ar = M-1;
    const short* xr = (const short*)(x + (size_t)ar*H) + quad*8;
    float4v acc[8];
    #pragma unroll
    for (int i = 0; i < 8; ++i) acc[i] = (float4v)0.f;
    #pragma unroll
    for (int kc = 0; kc < 4; ++kc){
        short8 a = *(const short8*)(xr + kc*32);
        #pragma unroll
        for (int nt = 0; nt < 8; ++nt){
            short8 b = *(const short8*)((const short*)(W + (size_t)(nt*16 + l15)*H) + kc*32 + quad*8);
            acc[nt] = __builtin_amdgcn_mfma_f32_16x16x32_bf16(a, b, acc[nt], 0, 0, 0);
        }
    }
    #pragma unroll
    for (int nt = 0; nt < 8; ++nt){
        int c = nt*16 + l15;
        float bv = bias[c];
        #pragma unroll
        for (int reg = 0; reg < 4; ++reg){
            int r = row0 + quad*4 + reg;
            if (r >= M) continue;
            out[(size_t)r*H + c] = f2bf(acc[nt][reg] + bv);
        }
    }
}

// ========== two-stage GEMM: y = x + relu(x@Wfo+bfo); then N outputs SEQUENTIALLY ==========
template<int NOUT2>
__global__ __launch_bounds__(256, 4) void gemm_fo_then(
    const ushort_t* __restrict__ x, int M,
    const ushort_t* __restrict__ Wfo, const float* __restrict__ bfo,
    const ushort_t* __restrict__ W2,            // [NOUT2*128][128]
    const float* __restrict__ b20, const float* __restrict__ b21, const float* __restrict__ b22,
    ushort_t* __restrict__ o0, ushort_t* __restrict__ o1, ushort_t* __restrict__ o2,
    float* __restrict__ o32)
{
    __shared__ ushort_t As[64][136];
    const int tid = threadIdx.x, w = tid >> 6, lane = tid & 63;
    const int l15 = lane & 15, quad = lane >> 4;
    const int row0 = blockIdx.x*64 + w*16;
    int ar = row0 + l15; if (ar > M-1) ar = M-1;
    const short* xr = (const short*)(x + (size_t)ar*H) + quad*8;
    {
        float4v acc[8];
        #pragma unroll
        for (int i = 0; i < 8; ++i) acc[i] = (float4v)0.f;
        #pragma unroll
        for (int kc = 0; kc < 4; ++kc){
            short8 a = *(const short8*)(xr + kc*32);
            #pragma unroll
            for (int nt = 0; nt < 8; ++nt){
                short8 b = *(const short8*)((const short*)(Wfo + (size_t)(nt*16 + l15)*H) + kc*32 + quad*8);
                acc[nt] = __builtin_amdgcn_mfma_f32_16x16x32_bf16(a, b, acc[nt], 0, 0, 0);
            }
        }
        #pragma unroll
        for (int nt = 0; nt < 8; ++nt){
            int c = nt*16 + l15;
            float bv = bfo[c];
            #pragma unroll
            for (int reg = 0; reg < 4; ++reg){
                int r = row0 + quad*4 + reg;
                float v = 0.f;
                if (r < M) v = fmaxf(acc[nt][reg] + bv, 0.f) + bf2f(x[(size_t)r*H + c]);
                As[w*16 + quad*4 + reg][c] = f2bf(v);
            }
        }
    }
    __syncthreads();
    #pragma unroll 1
    for (int n = 0; n < NOUT2; ++n){
        float4v o[8];
        #pragma unroll
        for (int i = 0; i < 8; ++i) o[i] = (float4v)0.f;
        #pragma unroll
        for (int kc = 0; kc < 4; ++kc){
            short8 a = *(const short8*)(&As[w*16 + l15][kc*32 + quad*8]);
            #pragma unroll
            for (int nt = 0; nt < 8; ++nt){
                short8 b = *(const short8*)((const short*)(W2 + (size_t)((n*8 + nt)*16 + l15)*H) + kc*32 + quad*8);
                o[nt] = __builtin_amdgcn_mfma_f32_16x16x32_bf16(a, b, o[nt], 0, 0, 0);
            }
        }
        ushort_t* out = (n == 0) ? o0 : ((n == 1) ? o1 : o2);
        const float* bb = (n == 0) ? b20 : ((n == 1) ? b21 : b22);
        #pragma unroll
        for (int nt = 0; nt < 8; ++nt){
            int c = nt*16 + l15;
            float bv = bb[c];
            #pragma unroll
            for (int reg = 0; reg < 4; ++reg){
                int r = row0 + quad*4 + reg;
                if (r >= M) continue;
                float v = o[nt][reg] + bv;
                if (o32 && n == 0) o32[(size_t)r*H + c] = v;
                else               out[(size_t)r*H + c] = f2bf(v);
            }
        }
    }
}

// ========== fused gather + MFMA GEMM v3 (2-edge unroll + index prefetch) ==========
template<int NOUT, int RELU, int STAGE2, int MINW>
__global__ __launch_bounds__(256, MINW) void k_conv_fused3(
    const ushort_t* __restrict__ x,
    const int* __restrict__ row_st, const int* __restrict__ srcs,
    const float* __restrict__ ces, const float* __restrict__ selfc,
    const ushort_t* __restrict__ W, const float* __restrict__ bias0,
    const float* __restrict__ bias1,
    const ushort_t* __restrict__ W2, const float* __restrict__ bias2,
    ushort_t* __restrict__ out0, ushort_t* __restrict__ out1)
{
    __shared__ ushort_t As[32][136];
    __shared__ ushort_t Bs[(NOUT==16)?32:1][(NOUT==16)?136:1];
    const int tid = threadIdx.x;
    const int node = tid >> 3, qq = tid & 7;   // 8 threads/node, 16 cols each
    const int g = blockIdx.x*32 + node;
    float acc[16];
    #pragma unroll
    for (int i = 0; i < 16; ++i) acc[i] = 0.f;
    if (g < NN){
        const uint4* xr = (const uint4*)(x + (size_t)g*H + qq*16);
        float sc = selfc[g];
        uint4 u0 = xr[0], u1 = xr[1];
        fma8(acc+0, u0, sc); fma8(acc+8, u1, sc);
        int e = row_st[g], e1 = row_st[g+1];
        int sA = 0, sB = 0; float cA = 0.f, cB = 0.f;
        if (e < e1){ sA = srcs[e]; cA = ces[e]; }
        if (e + 1 < e1){ sB = srcs[e+1]; cB = ces[e+1]; }
        while (e + 2 <= e1){
            // prefetch next pair's indices (overlaps with data-load latency)
            int sA2 = 0, sB2 = 0; float cA2 = 0.f, cB2 = 0.f;
            if (e + 2 < e1){ sA2 = srcs[e+2]; cA2 = ces[e+2]; }
            if (e + 3 < e1){ sB2 = srcs[e+3]; cB2 = ces[e+3]; }
            const uint4* pa = (const uint4*)(x + (size_t)sA*H + qq*16);
            const uint4* pb = (const uint4*)(x + (size_t)sB*H + qq*16);
            uint4 a0 = pa[0], a1 = pa[1];
            uint4 c0 = pb[0], c1 = pb[1];
            fma8(acc+0, a0, cA); fma8(acc+8, a1, cA);
            fma8(acc+0, c0, cB); fma8(acc+8, c1, cB);
            sA = sA2; sB = sB2; cA = cA2; cB = cB2;
            e += 2;
        }
        if (e < e1){
            const uint4* pa = (const uint4*)(x + (size_t)sA*H + qq*16);
            uint4 a0 = pa[0], a1 = pa[1];
            fma8(acc+0, a0, cA); fma8(acc+8, a1, cA);
        }
    }
    {
        uint_t* dst = (uint_t*)&As[node][qq*16];
        #pragma unroll
        for (int i = 0; i < 8; ++i)
            dst[i] = (uint_t)f2bf(acc[2*i]) | ((uint_t)f2bf(acc[2*i+1]) << 16);
    }
    __syncthreads();
    const int w = tid >> 6, lane = tid & 63, l15 = lane & 15, quad = lane >> 4;
    const int rt = w & 1;                  // row tile (16 rows)
    constexpr int NT = NOUT/2;             // col tiles per wave
    const int ct0 = (w >> 1) * NT;
    float4v o[NT];
    #pragma unroll
    for (int t = 0; t < NT; ++t) o[t] = (float4v)0.f;
    #pragma unroll
    for (int kc = 0; kc < 4; ++kc){
        short8 a = *(const short8*)(&As[rt*16 + l15][kc*32 + quad*8]);
        #pragma unroll
        for (int t = 0; t < NT; ++t){
            short8 bfr = *(const short8*)(W + (size_t)((ct0 + t)*16 + l15)*H + kc*32 + quad*8);
            o[t] = __builtin_amdgcn_mfma_f32_16x16x32_bf16(a, bfr, o[t], 0, 0, 0);
        }
    }
    __syncthreads();
    #pragma unroll
    for (int t = 0; t < NT; ++t){
        int cg = (ct0 + t)*16 + l15;
        #pragma unroll
        for (int r = 0; r < 4; ++r){
            float v;
            if (NOUT == 8 || cg < 128){
                v = o[t][r] + bias0[cg];
                if (RELU) v = fmaxf(v, 0.f);
                As[rt*16 + quad*4 + r][cg] = f2bf(v);
            } else {
                v = o[t][r] + bias1[cg - 128];
                if (RELU) v = fmaxf(v, 0.f);
                Bs[rt*16 + quad*4 + r][cg - 128] = f2bf(v);
            }
        }
    }
    __syncthreads();
    if (STAGE2){
        float4v o2[4];
        #pragma unroll
        for (int t = 0; t < 4; ++t) o2[t] = (float4v)0.f;
        const int ct2 = (w >> 1) * 4;
        #pragma unroll
        for (int kc = 0; kc < 4; ++kc){
            short8 a = *(const short8*)(&As[rt*16 + l15][kc*32 + quad*8]);
            #pragma unroll
            for (int t = 0; t < 4; ++t){
                short8 bfr = *(const short8*)(W2 + (size_t)((ct2 + t)*16 + l15)*H + kc*32 + quad*8);
                o2[t] = __builtin_amdgcn_mfma_f32_16x16x32_bf16(a, bfr, o2[t], 0, 0, 0);
            }
        }
        __syncthreads();
        #pragma unroll
        for (int t = 0; t < 4; ++t){
            int cg = (ct2 + t)*16 + l15;
            #pragma unroll
            for (int r = 0; r < 4; ++r)
                As[rt*16 + quad*4 + r][cg] = f2bf(o2[t][r] + bias2[cg]);
        }
        __syncthreads();
    }
    if (g < NN){
        uint4* op = (uint4*)(out0 + (size_t)g*H + qq*16);
        const uint4* sp = (const uint4*)&As[node][qq*16];
        op[0] = sp[0]; op[1] = sp[1];
        if (NOUT == 16){
            uint4* oq = (uint4*)(out1 + (size_t)g*H + qq*16);
            const uint4* sq = (const uint4*)&Bs[node][qq*16];
            oq[0] = sq[0]; oq[1] = sq[1];
        }
    }
}

// ========== conv0: gather padded-64 bf16 rows + MFMA GEMM (K=64) ==========
__global__ __launch_bounds__(256, 8) void k_conv0b(
    const ushort_t* __restrict__ x,   // [NN][64] bf16
    const int* __restrict__ row_st, const int* __restrict__ srcs,
    const float* __restrict__ ces, const float* __restrict__ selfc,
    const ushort_t* __restrict__ W,   // [128][64]
    const float* __restrict__ bias,
    ushort_t* __restrict__ out)
{
    __shared__ ushort_t As[32][136];
    const int tid = threadIdx.x;
    const int node = tid >> 3, qq = tid & 7;   // 8 cols (1 uint4) each
    const int g = blockIdx.x*32 + node;
    float acc[8];
    #pragma unroll
    for (int i = 0; i < 8; ++i) acc[i] = 0.f;
    if (g < NN){
        const uint4* xr = (const uint4*)(x + (size_t)g*64 + qq*8);
        float sc = selfc[g];
        fma8(acc, xr[0], sc);
        int e = row_st[g], e1 = row_st[g+1];
        int sA = 0, sB = 0; float cA = 0.f, cB = 0.f;
        if (e < e1){ sA = srcs[e]; cA = ces[e]; }
        if (e + 1 < e1){ sB = srcs[e+1]; cB = ces[e+1]; }
        while (e + 2 <= e1){
            int sA2 = 0, sB2 = 0; float cA2 = 0.f, cB2 = 0.f;
            if (e + 2 < e1){ sA2 = srcs[e+2]; cA2 = ces[e+2]; }
            if (e + 3 < e1){ sB2 = srcs[e+3]; cB2 = ces[e+3]; }
            uint4 a0 = *(const uint4*)(x + (size_t)sA*64 + qq*8);
            uint4 c0 = *(const uint4*)(x + (size_t)sB*64 + qq*8);
            fma8(acc, a0, cA);
            fma8(acc, c0, cB);
            sA = sA2; sB = sB2; cA = cA2; cB = cB2;
            e += 2;
        }
        if (e < e1){
            uint4 a0 = *(const uint4*)(x + (size_t)sA*64 + qq*8);
            fma8(acc, a0, cA);
        }
    }
    {
        uint_t* dst = (uint_t*)&As[node][qq*8];
        #pragma unroll
        for (int i = 0; i < 4; ++i)
            dst[i] = (uint_t)f2bf(acc[2*i]) | ((uint_t)f2bf(acc[2*i+1]) << 16);
    }
    __syncthreads();
    const int w = tid >> 6, lane = tid & 63, l15 = lane & 15, quad = lane >> 4;
    const int rt = w & 1;
    const int ct0 = (w >> 1) * 4;
    float4v o[4];
    #pragma unroll
    for (int t = 0; t < 4; ++t) o[t] = (float4v)0.f;
    #pragma unroll
    for (int kc = 0; kc < 2; ++kc){
        short8 a = *(const short8*)(&As[rt*16 + l15][kc*32 + quad*8]);
        #pragma unroll
        for (int t = 0; t < 4; ++t){
            short8 bfr = *(const short8*)(W + (size_t)((ct0 + t)*16 + l15)*64 + kc*32 + quad*8);
            o[t] = __builtin_amdgcn_mfma_f32_16x16x32_bf16(a, bfr, o[t], 0, 0, 0);
        }
    }
    __syncthreads();
    #pragma unroll
    for (int t = 0; t < 4; ++t){
        int cg = (ct0 + t)*16 + l15;
        #pragma unroll
        for (int r = 0; r < 4; ++r)
            As[rt*16 + quad*4 + r][cg] = f2bf(fmaxf(o[t][r] + bias[cg], 0.f));
    }
    __syncthreads();
    if (g < NN){
        uint4* op = (uint4*)(out + (size_t)g*H + qq*16);
        const uint4* sp = (const uint4*)&As[node][qq*16];
        op[0] = sp[0]; op[1] = sp[1];
    }
}

// ========== MFMA flash attention ==========
template<int NK>
__global__ __launch_bounds__(256) void k_attn_mfma(
    const ushort_t* __restrict__ Q, int qbs,
    const ushort_t* __restrict__ K, const ushort_t* __restrict__ V,
    ushort_t* __restrict__ out, int nq)
{
    constexpr int NKT = (NK + 15) / 16;
    constexpr int NKC = (NK + 31) / 32;
    __shared__ ushort_t Ks[2][208][24];
    __shared__ ushort_t Vs[2][16][232];
    __shared__ ushort_t Ps[4][16][232];
    int b = blockIdx.x >> 2, hp = blockIdx.x & 3;
    int h0 = hp*2;
    int tid = threadIdx.x;
    {
        uint_t* p = (uint_t*)&Ps[0][0][0];
        for (int i = tid; i < 4*16*232/2; i += 256) p[i] = 0;
    }
    const ushort_t* Kb = K + (size_t)b*NK*H + h0*16;
    for (int idx = tid; idx < NK*8; idx += 256){
        int key = idx >> 3, p = idx & 7;
        int hh = p >> 2, dl = (p & 3)*4;
        const uint_t* src = (const uint_t*)(Kb + (size_t)key*H + hh*16 + dl);
        uint_t* d = (uint_t*)&Ks[hh][key][dl];
        d[0] = src[0]; d[1] = src[1];
    }
    const ushort_t* Vb = V + (size_t)b*NK*H + h0*16;
    for (int idx = tid; idx < NK*8; idx += 256){
        int key = idx >> 3, p = idx & 7;
        int hh = p >> 2, dl = (p & 3)*4;
        const ushort_t* src = Vb + (size_t)key*H + hh*16 + dl;
        Vs[hh][dl+0][key] = src[0];
        Vs[hh][dl+1][key] = src[1];
        Vs[hh][dl+2][key] = src[2];
        Vs[hh][dl+3][key] = src[3];
    }
    for (int idx = tid; idx < 2*16*(232-NK); idx += 256){
        int key = NK + idx % (232-NK), r = idx / (232-NK);
        Vs[r>>4][r&15][key] = 0;
    }
    __syncthreads();

    int w = tid >> 6, lane = tid & 63;
    int hh = w >> 1, half = w & 1;
    int h = h0 + hh;
    int l15 = lane & 15, quad = lane >> 4;
    bool klow = (quad < 2);
    int nqt = (nq + 15) >> 4;
    int split = (nqt + 1) >> 1;
    int qt0 = half ? split : 0;
    int qt1 = half ? nqt : split;
    for (int qt = qt0; qt < qt1; ++qt){
        int qr = qt*16 + l15; if (qr > nq-1) qr = nq-1;
        short8 av = *(const short8*)(Q + (size_t)b*qbs + (size_t)qr*H + h*16 + (quad & 1)*8);
        short8 zero8 = (short8)0;
        short8 afrag = klow ? av : zero8;
        float4v s[NKT];
        #pragma unroll
        for (int kt = 0; kt < NKT; ++kt){
            short8 bv = *(const short8*)(&Ks[hh][kt*16 + l15][(quad & 1)*8]);
            short8 bfrag = klow ? bv : zero8;
            s[kt] = __builtin_amdgcn_mfma_f32_16x16x32_bf16(afrag, bfrag, (float4v)0.f, 0, 0, 0);
        }
        float mx[4] = {-1e30f, -1e30f, -1e30f, -1e30f};
        #pragma unroll
        for (int kt = 0; kt < NKT; ++kt){
            if (kt*16 + l15 >= NK){ s[kt][0]=-1e30f; s[kt][1]=-1e30f; s[kt][2]=-1e30f; s[kt][3]=-1e30f; }
            #pragma unroll
            for (int r = 0; r < 4; ++r) mx[r] = fmaxf(mx[r], s[kt][r]);
        }
        #pragma unroll
        for (int off = 1; off < 16; off <<= 1){
            #pragma unroll
            for (int r = 0; r < 4; ++r) mx[r] = fmaxf(mx[r], __shfl_xor(mx[r], off));
        }
        float sum[4] = {0.f, 0.f, 0.f, 0.f};
        #pragma unroll
        for (int kt = 0; kt < NKT; ++kt){
            #pragma unroll
            for (int r = 0; r < 4; ++r){
                float e = __expf((s[kt][r] - mx[r]) * SCALE);
                sum[r] += e;
                Ps[w][quad*4 + r][kt*16 + l15] = f2bf(e);
            }
        }
        #pragma unroll
        for (int off = 1; off < 16; off <<= 1){
            #pragma unroll
            for (int r = 0; r < 4; ++r) sum[r] += __shfl_xor(sum[r], off);
        }
        float4v o = (float4v)0.f;
        #pragma unroll
        for (int kc = 0; kc < NKC; ++kc){
            short8 pa = *(const short8*)(&Ps[w][l15][kc*32 + quad*8]);
            short8 vb = *(const short8*)(&Vs[hh][l15][kc*32 + quad*8]);
            o = __builtin_amdgcn_mfma_f32_16x16x32_bf16(pa, vb, o, 0, 0, 0);
        }
        #pragma unroll
        for (int r = 0; r < 4; ++r){
            int row = qt*16 + quad*4 + r;
            if (row < nq){
                float qv = bf2f(Q[(size_t)b*qbs + (size_t)row*H + h*16 + l15]);
                out[((size_t)b*nq + row)*H + h*16 + l15] = f2bf(qv + o[r] / sum[r]);
            }
        }
    }
}

// ---------------- hERG (fp32) ----------------
__global__ void k_herg(const float* __restrict__ em, const float* __restrict__ W,
                       const float* __restrict__ b, float* __restrict__ outv)
{
    __shared__ float e[1280];
    int t = threadIdx.x;
    for (int i = t; i < 1280; i += 128) e[i] = em[i];
    __syncthreads();
    float acc = 0.f;
    for (int k = 0; k < 1280; ++k) acc += e[k] * W[(size_t)t*1280 + k];
    outv[t] = fmaxf(acc + b[t], 0.f);
}

// ---------------- head MLP (fp32) ----------------
__global__ __launch_bounds__(128) void k_final(const float* __restrict__ lin2out,
    const float* __restrict__ hergv,
    const float* __restrict__ hoW, const float* __restrict__ hob,
    const float* __restrict__ fcW, const float* __restrict__ fcb,
    const float* __restrict__ sW,  const float* __restrict__ sb,
    float* __restrict__ outp)
{
    int b = blockIdx.x, t = threadIdx.x;
    __shared__ float v256[256];
    __shared__ float tt[128];
    __shared__ float red[128];
    v256[t]       = lin2out[(size_t)b*H + t];
    v256[128 + t] = hergv[t];
    __syncthreads();
    float acc = 0.f;
    for (int k = 0; k < 256; ++k) acc += v256[k] * hoW[(size_t)t*256 + k];
    tt[t] = fmaxf(acc + hob[t], 0.f);
    __syncthreads();
    acc = 0.f;
    for (int k = 0; k < 128; ++k) acc += tt[k] * fcW[(size_t)t*128 + k];
    float uv = fmaxf(acc + fcb[t], 0.f);
    red[t] = uv * sW[t];
    __syncthreads();
    for (int s = 64; s > 0; s >>= 1){
        if (t < s) red[t] += red[t + s];
        __syncthreads();
    }
    if (t == 0){
        float logit = red[0] + sb[0];
        outp[b] = 1.f / (1.f + expf(-logit));
    }
}

extern "C" void kernel_launch(void* const* d_in, const int* in_sizes, int n_in,
                              void* d_out, int out_size, void* d_ws, size_t ws_size,
                              hipStream_t stream)
{
    (void)in_sizes; (void)n_in; (void)out_size; (void)ws_size;
    const float* herg_em = (const float*)d_in[0];
    const float* x_in    = (const float*)d_in[1];
    const float* convW[4] = {(const float*)d_in[4], (const float*)d_in[6], (const float*)d_in[8], (const float*)d_in[10]};
    const float* convB[4] = {(const float*)d_in[5], (const float*)d_in[7], (const float*)d_in[9], (const float*)d_in[11]};
    const float* lin1W = (const float*)d_in[12]; const float* lin1b = (const float*)d_in[13];
    const float* lin2W = (const float*)d_in[14]; const float* lin2b = (const float*)d_in[15];
    const float* S1    = (const float*)d_in[16];
    const float* p1fqW = (const float*)d_in[17]; const float* p1fqb = (const float*)d_in[18];
    const float* p1kW  = (const float*)d_in[19]; const float* p1kb  = (const float*)d_in[20];
    const float* p1vW  = (const float*)d_in[21]; const float* p1vb  = (const float*)d_in[22];
    const float* p1foW = (const float*)d_in[23]; const float* p1fob = (const float*)d_in[24];
    const float* sfqW  = (const float*)d_in[25]; const float* sfqb  = (const float*)d_in[26];
    const float* skW   = (const float*)d_in[27]; const float* skb   = (const float*)d_in[28];
    const float* svW   = (const float*)d_in[29]; const float* svb   = (const float*)d_in[30];
    const float* sfoW  = (const float*)d_in[31]; const float* sfob  = (const float*)d_in[32];
    const float* p2fqW = (const float*)d_in[33]; const float* p2fqb = (const float*)d_in[34];
    const float* p2kW  = (const float*)d_in[35]; const float* p2kb  = (const float*)d_in[36];
    const float* p2vW  = (const float*)d_in[37]; const float* p2vb  = (const float*)d_in[38];
    const float* p2foW = (const float*)d_in[39]; const float* p2fob = (const float*)d_in[40];
    const float* S2    = (const float*)d_in[41];
    const float* hlW   = (const float*)d_in[42]; const float* hlb   = (const float*)d_in[43];
    const float* hoW   = (const float*)d_in[44]; const float* hob   = (const float*)d_in[45];
    const float* fcW   = (const float*)d_in[46]; const float* fcb   = (const float*)d_in[47];
    const float* sW    = (const float*)d_in[48]; const float* sb    = (const float*)d_in[49];
    const int*  ei    = (const int*)d_in[50];
    const int*  esrc  = ei;
    const int*  edst  = ei + NE;
    float* outp = (float*)d_out;

    // -------- workspace layout (byte offsets, 16B-aligned) --------
    char* WS = (char*)d_ws;
    int*   counts = (int*)(WS + 0);
    int*   cursor = (int*)(WS + 400384);
    int*   row_st = (int*)(WS + 800768);
    int*   bSums  = (int*)(WS + 1201152);
    int*   bOff   = (int*)(WS + 1203200);
    float* dinv   = (float*)(WS + 1205248);
    float* selfc  = (float*)(WS + 1605632);
    int*   srcs_s = (int*)(WS + 2005632);
    float* ce_s   = (float*)(WS + 3605632);
    ushort_t* wbf = (ushort_t*)(WS + 5205632); // 17*16384
    ushort_t* w0bf= (ushort_t*)(WS + 5762688);
    ushort_t* s1bf= (ushort_t*)(WS + 5779072);
    ushort_t* s2bf= (ushort_t*)(WS + 5798272);
    ushort_t* q0  = (ushort_t*)(WS + 5798528);
    ushort_t* q2  = (ushort_t*)(WS + 5817728);
    float* hergv  = (float*)(WS + 5817984);
    float* l2out  = (float*)(WS + 5818496);
    ushort_t* xb64= (ushort_t*)(WS + 6074496); // NN*64 bf16 padded raw x
    ushort_t* b0  = (ushort_t*)(WS + 18874496);// NN*128
    ushort_t* b1  = (ushort_t*)(WS + 44474496);
    ushort_t* b2  = (ushort_t*)(WS + 70074496);
    ushort_t* xA  = (ushort_t*)(WS + 95674496);   // 37504*128
    ushort_t* xB  = (ushort_t*)(WS + 105275520);
    ushort_t* xQ  = (ushort_t*)(WS + 114876544);
    ushort_t* xK  = (ushort_t*)(WS + 124477568);
    ushort_t* xV  = (ushort_t*)(WS + 134078592);

    const int gN   = (NN + 255)/256;       // 391
    const int gE   = (NE + 255)/256;       // 1563
    const int gC   = (NN + 31)/32;         // 3125
    const int gXb  = (NB*NS + 63)/64;      // 586

    // ---- CSR build ----
    k_zero_i<<<gN, 256, 0, stream>>>(counts, NN);
    k_hist  <<<gE, 256, 0, stream>>>(counts, edst, NE);
    k_scan1 <<<gN, 256, 0, stream>>>(counts, row_st, bSums, dinv, selfc, NN);
    k_scan2 <<<1, 512, 0, stream>>>(bSums, bOff, gN);
    k_scan3 <<<gN, 256, 0, stream>>>(row_st, cursor, bOff, NN, NE);
    k_fillcsr<<<gE, 256, 0, stream>>>(esrc, edst, dinv, cursor, srcs_s, ce_s, NE);

    // ---- merged weight/input conversions (1 launch) ----
    CvtArgs ca;
    ca.w[0]=convW[1]; ca.w[1]=convW[2]; ca.w[2]=convW[3]; ca.w[3]=lin1W; ca.w[4]=lin2W;
    ca.w[5]=p1kW; ca.w[6]=p1vW; ca.w[7]=p1foW;
    ca.w[8]=sfqW; ca.w[9]=skW; ca.w[10]=svW; ca.w[11]=sfoW;
    ca.w[12]=p2kW; ca.w[13]=p2vW; ca.w[14]=p2foW; ca.w[15]=p1fqW; ca.w[16]=p2fqW;
    ca.w0 = convW[0]; ca.s1 = S1; ca.s2 = S2; ca.x37 = x_in;
    const int cvtTotal = CVT_W + CVT_W0 + CVT_S1 + CVT_S2 + CVT_X;
    k_cvt_all<<<(cvtTotal + 255)/256, 256, 0, stream>>>(ca, wbf, w0bf, s1bf, s2bf, xb64);

    // ---- seed-Q projections (1 launch) + hERG ----
    k_seedq<<<3, 256, 0, stream>>>(s1bf, s2bf, wbf + (size_t)15*16384, p1fqb,
                                   wbf + (size_t)16*16384, p2fqb, q0, q2);
    k_herg<<<1, 128, 0, stream>>>(herg_em, hlW, hlb, hergv);

    // ---- conv0 (fused gather64 + GEMM) -> b0 ----
    k_conv0b<<<gC, 256, 0, stream>>>(xb64, row_st, srcs_s, ce_s, selfc, w0bf, convB[0], b0);
    // ---- conv1, conv2 ----
    k_conv_fused3<8,1,0,8><<<gC, 256, 0, stream>>>(b0, row_st, srcs_s, ce_s, selfc,
        wbf + (size_t)0*16384, convB[1], nullptr, nullptr, nullptr, b1, nullptr);
    k_conv_fused3<8,1,0,8><<<gC, 256, 0, stream>>>(b1, row_st, srcs_s, ce_s, selfc,
        wbf + (size_t)1*16384, convB[2], nullptr, nullptr, nullptr, b0, nullptr);
    // ---- conv3 + lin1 fused -> hx in b1 ----
    k_conv_fused3<8,1,1,8><<<gC, 256, 0, stream>>>(b0, row_st, srcs_s, ce_s, selfc,
        wbf + (size_t)2*16384, convB[3], nullptr, wbf + (size_t)3*16384, lin1b, b1, nullptr);
    // ---- pma1 K,V: fused shared-gather + dual GEMM (K->b2, V->b0) ----
    k_conv_fused3<16,0,0,4><<<gC, 256, 0, stream>>>(b1, row_st, srcs_s, ce_s, selfc,
        wbf + (size_t)5*16384, p1kb, p1vb, nullptr, nullptr, b2, b0);
    // ---- GMPool_G attention -> xA ----
    k_attn_mfma<200><<<NB*4, 256, 0, stream>>>(q0, 0, b2, b0, xA, NS);
    // ---- fused: xb1 = xA + relu(xA@p1fo+b); then SAB Q,K,V ----
    gemm_fo_then<3><<<gXb, 256, 0, stream>>>(xA, NB*NS, wbf + (size_t)7*16384, p1fob,
        wbf + (size_t)8*16384, sfqb, skb, svb, xQ, xK, xV, nullptr);
    // ---- SAB attention -> xB ----
    k_attn_mfma<75><<<NB*4, 256, 0, stream>>>(xQ, NS*H, xK, xV, xB, NS);
    // ---- fused: xb2 = xB + relu(xB@sfo+b); then PMA2 K,V ----
    gemm_fo_then<2><<<gXb, 256, 0, stream>>>(xB, NB*NS, wbf + (size_t)11*16384, sfob,
        wbf + (size_t)12*16384, p2kb, p2vb, nullptr, xK, xV, nullptr, nullptr);
    // ---- GMPool_I attention -> xA [500,128] ----
    k_attn_mfma<75><<<NB*4, 256, 0, stream>>>(q2, 0, xK, xV, xA, 1);
    // ---- fused: xb3 = xA + relu(xA@p2fo+b); then lin2 (fp32 out) ----
    gemm_fo_then<1><<<(NB+63)/64, 256, 0, stream>>>(xA, NB, wbf + (size_t)14*16384, p2fob,
        wbf + (size_t)4*16384, lin2b, nullptr, nullptr, nullptr, nullptr, nullptr, l2out);
    // ---- head ----
    k_final<<<NB, 128, 0, stream>>>(l2out, hergv, hoW, hob, fcW, fcb, sW, sb, outp);
}